// Round 2
// baseline (1194.346 us; speedup 1.0000x reference)
//
#include <hip/hip_runtime.h>
#include <hip/hip_bf16.h>

#define N_NODES  100000
#define N_EDGES  3200000
#define IN_FEAT  512
#define HIDDEN   64
#define N_GRAPHS 2048

// ---------------------------------------------------------------- utilities
__global__ __launch_bounds__(256) void zero_u32(unsigned* __restrict__ p, int n) {
    int i = blockIdx.x * 256 + threadIdx.x;
    if (i < n) p[i] = 0u;
}

__global__ __launch_bounds__(256) void init_deg(int* __restrict__ degi, int n) {
    int i = blockIdx.x * 256 + threadIdx.x;
    if (i < n) degi[i] = 1;              // self-loop contributes 1 to in-degree
}

// 4 edges per thread via int4 loads
__global__ __launch_bounds__(256) void deg_count(const int* __restrict__ dst,
                                                 int* __restrict__ degi, int e) {
    int i = (blockIdx.x * 256 + threadIdx.x) * 4;
    if (i + 4 <= e) {
        int4 d = *(const int4*)(dst + i);
        atomicAdd(&degi[d.x], 1);
        atomicAdd(&degi[d.y], 1);
        atomicAdd(&degi[d.z], 1);
        atomicAdd(&degi[d.w], 1);
    } else {
        for (int j = i; j < e; j++) atomicAdd(&degi[dst[j]], 1);
    }
}

__global__ __launch_bounds__(256) void compute_dinv(const int* __restrict__ degi,
                                                    float* __restrict__ dinv, int n) {
    int i = blockIdx.x * 256 + threadIdx.x;
    if (i < n) dinv[i] = 1.0f / sqrtf((float)degi[i]);
}

__global__ __launch_bounds__(256) void count_graphs(const int* __restrict__ batch,
                                                    int* __restrict__ cntg, int n) {
    int i = blockIdx.x * 256 + threadIdx.x;
    if (i < n) atomicAdd(&cntg[batch[i]], 1);
}

// ---------------------------------------------------------------- scan (CSR offsets)
#define SCAN_CHUNK 2048

__global__ __launch_bounds__(256) void scan_block_sums(const int* __restrict__ degi,
                                                       int* __restrict__ bsums, int n) {
    __shared__ int sdata[256];
    int t = threadIdx.x;
    int base = blockIdx.x * SCAN_CHUNK;
    int s = 0;
    for (int i = 0; i < 8; i++) {
        int idx = base + t * 8 + i;
        if (idx < n) s += degi[idx] - 1;
    }
    sdata[t] = s;
    __syncthreads();
    for (int off = 128; off > 0; off >>= 1) {
        if (t < off) sdata[t] += sdata[t + off];
        __syncthreads();
    }
    if (t == 0) bsums[blockIdx.x] = sdata[0];
}

__global__ void scan_bsums(int* __restrict__ bsums, int nb) {
    if (blockIdx.x == 0 && threadIdx.x == 0) {
        int acc = 0;
        for (int i = 0; i < nb; i++) { int v = bsums[i]; bsums[i] = acc; acc += v; }
    }
}

__global__ __launch_bounds__(256) void scan_write(const int* __restrict__ degi,
                                                  const int* __restrict__ bsums,
                                                  int* __restrict__ row_start,
                                                  int* __restrict__ cur, int n) {
    __shared__ int sthread[256];
    int t = threadIdx.x;
    int base = blockIdx.x * SCAN_CHUNK;
    int local[8];
    int s = 0;
    for (int i = 0; i < 8; i++) {
        int idx = base + t * 8 + i;
        int c = (idx < n) ? (degi[idx] - 1) : 0;
        local[i] = s;
        s += c;
    }
    sthread[t] = s;
    __syncthreads();
    for (int off = 1; off < 256; off <<= 1) {
        int v = (t >= off) ? sthread[t - off] : 0;
        __syncthreads();
        sthread[t] += v;
        __syncthreads();
    }
    int off0 = bsums[blockIdx.x] + sthread[t] - s;   // exclusive prefix for this thread
    for (int i = 0; i < 8; i++) {
        int idx = base + t * 8 + i;
        if (idx < n) {
            int rs = off0 + local[i];
            row_start[idx] = rs;
            cur[idx] = rs;
        }
    }
}

// src-only CSR fill: ONE 4B scattered store per edge (csr_w eliminated —
// dinv is folded into the GEMM epilogues instead)
__global__ __launch_bounds__(256) void csr_fill(const int* __restrict__ src,
                                                const int* __restrict__ dst,
                                                int* __restrict__ cur,
                                                int* __restrict__ csr_src, int e) {
    int i = blockIdx.x * 256 + threadIdx.x;
    if (i >= e) return;
    int d = dst[i];
    int s = src[i];
    int p = atomicAdd(&cur[d], 1);
    csr_src[p] = s;
}

// ---------------------------------------------------------------- fp32 GEMM: Y[n,64] = dinv[n] * (X[n,K] @ W[K,64])
template <int K>
__global__ __launch_bounds__(256) void gemm_xw(const float* __restrict__ X,
                                               const float* __restrict__ W,
                                               const float* __restrict__ dinv,
                                               float* __restrict__ Y, int nrows) {
    constexpr int BM = 128;
    __shared__ float xs[BM][68];   // [row][k] pad 64 -> 68
    __shared__ float ws[64][64];   // [k][col]
    const int t = threadIdx.x;
    const int row0 = blockIdx.x * BM;
    const int ct = t & 15;         // cols ct*4 .. ct*4+3
    const int rt = t >> 4;         // rows rt + 16*j, j = 0..7
    float acc[8][4] = {};

#pragma unroll 1
    for (int k0 = 0; k0 < K; k0 += 64) {
#pragma unroll
        for (int p = 0; p < 4; p++) {
            int f = t + p * 256;
            int kk = f >> 4, cq = f & 15;
            *(float4*)&ws[kk][cq * 4] =
                *(const float4*)(W + (size_t)(k0 + kk) * 64 + cq * 4);
        }
#pragma unroll
        for (int p = 0; p < 8; p++) {
            int f = t + p * 256;
            int r = f >> 4, kq = f & 15;
            int gr = row0 + r;
            float4 v = make_float4(0.f, 0.f, 0.f, 0.f);
            if (gr < nrows) v = *(const float4*)(X + (size_t)gr * K + k0 + kq * 4);
            *(float4*)&xs[r][kq * 4] = v;
        }
        __syncthreads();

#pragma unroll
        for (int kq = 0; kq < 16; kq++) {
            float4 wv0 = *(float4*)&ws[kq * 4 + 0][ct * 4];
            float4 wv1 = *(float4*)&ws[kq * 4 + 1][ct * 4];
            float4 wv2 = *(float4*)&ws[kq * 4 + 2][ct * 4];
            float4 wv3 = *(float4*)&ws[kq * 4 + 3][ct * 4];
#pragma unroll
            for (int j = 0; j < 8; j++) {
                float4 xv = *(float4*)&xs[rt + 16 * j][kq * 4];
                acc[j][0] = fmaf(xv.x, wv0.x, acc[j][0]);
                acc[j][1] = fmaf(xv.x, wv0.y, acc[j][1]);
                acc[j][2] = fmaf(xv.x, wv0.z, acc[j][2]);
                acc[j][3] = fmaf(xv.x, wv0.w, acc[j][3]);
                acc[j][0] = fmaf(xv.y, wv1.x, acc[j][0]);
                acc[j][1] = fmaf(xv.y, wv1.y, acc[j][1]);
                acc[j][2] = fmaf(xv.y, wv1.z, acc[j][2]);
                acc[j][3] = fmaf(xv.y, wv1.w, acc[j][3]);
                acc[j][0] = fmaf(xv.z, wv2.x, acc[j][0]);
                acc[j][1] = fmaf(xv.z, wv2.y, acc[j][1]);
                acc[j][2] = fmaf(xv.z, wv2.z, acc[j][2]);
                acc[j][3] = fmaf(xv.z, wv2.w, acc[j][3]);
                acc[j][0] = fmaf(xv.w, wv3.x, acc[j][0]);
                acc[j][1] = fmaf(xv.w, wv3.y, acc[j][1]);
                acc[j][2] = fmaf(xv.w, wv3.z, acc[j][2]);
                acc[j][3] = fmaf(xv.w, wv3.w, acc[j][3]);
            }
        }
        __syncthreads();
    }

#pragma unroll
    for (int j = 0; j < 8; j++) {
        int gr = row0 + rt + 16 * j;
        if (gr < nrows) {
            float dv = dinv[gr];
            *(float4*)(Y + (size_t)gr * 64 + ct * 4) =
                make_float4(acc[j][0] * dv, acc[j][1] * dv, acc[j][2] * dv, acc[j][3] * dv);
        }
    }
}

// ---------------------------------------------------------------- GCN gather (SpMM), wave per node
// g is pre-scaled by dinv.  out[n,f] = dinv[n]*(g[n,f] + sum_src g[src,f]) + bias[f]
template <bool RELU, bool POOL>
__global__ __launch_bounds__(256) void gcn_gather(const float* __restrict__ g,
                                                  const float* __restrict__ dinv,
                                                  const int* __restrict__ row_start,
                                                  const int* __restrict__ degi,
                                                  const int* __restrict__ csr_src,
                                                  const float* __restrict__ bias,
                                                  float* __restrict__ out,
                                                  float* __restrict__ pooled,
                                                  const int* __restrict__ batch, int n) {
    int node = (blockIdx.x * 256 + threadIdx.x) >> 6;
    int lane = threadIdx.x & 63;
    if (node >= n) return;

    int start = row_start[node];
    int de = degi[node] - 1;
    float dn = dinv[node];

    float acc0 = g[(size_t)node * 64 + lane];   // self-loop term (pre-scaled)
    float acc1 = 0.f, acc2 = 0.f, acc3 = 0.f;
    float acc4 = 0.f, acc5 = 0.f, acc6 = 0.f, acc7 = 0.f;

    for (int c = 0; c < de; c += 64) {
        int m = min(64, de - c);
        int sv = 0;
        if (lane < m) sv = csr_src[start + c + lane];
        int j = 0;
        for (; j + 8 <= m; j += 8) {
            int s0 = __shfl(sv, j + 0);
            int s1 = __shfl(sv, j + 1);
            int s2 = __shfl(sv, j + 2);
            int s3 = __shfl(sv, j + 3);
            int s4 = __shfl(sv, j + 4);
            int s5 = __shfl(sv, j + 5);
            int s6 = __shfl(sv, j + 6);
            int s7 = __shfl(sv, j + 7);
            float v0 = g[(size_t)s0 * 64 + lane];
            float v1 = g[(size_t)s1 * 64 + lane];
            float v2 = g[(size_t)s2 * 64 + lane];
            float v3 = g[(size_t)s3 * 64 + lane];
            float v4 = g[(size_t)s4 * 64 + lane];
            float v5 = g[(size_t)s5 * 64 + lane];
            float v6 = g[(size_t)s6 * 64 + lane];
            float v7 = g[(size_t)s7 * 64 + lane];
            acc0 += v0; acc1 += v1; acc2 += v2; acc3 += v3;
            acc4 += v4; acc5 += v5; acc6 += v6; acc7 += v7;
        }
        for (; j < m; j++) {
            int s = __shfl(sv, j);
            acc0 += g[(size_t)s * 64 + lane];
        }
    }
    float acc = ((acc0 + acc1) + (acc2 + acc3)) + ((acc4 + acc5) + (acc6 + acc7));
    float o = fmaf(dn, acc, bias[lane]);
    if (RELU) o = fmaxf(o, 0.f);
    if (POOL) {
        atomicAdd(&pooled[(size_t)batch[node] * 64 + lane], o);
    } else {
        out[(size_t)node * 64 + lane] = o;
    }
}

// ---------------------------------------------------------------- final FC, wave per graph
__global__ __launch_bounds__(256) void final_fc(const float* __restrict__ pooled,
                                                const int* __restrict__ cntg,
                                                const float* __restrict__ fc_w,
                                                const float* __restrict__ fc_b,
                                                float* __restrict__ out, int g) {
    int gid = (blockIdx.x * 256 + threadIdx.x) >> 6;
    int lane = threadIdx.x & 63;
    if (gid >= g) return;
    float c = fmaxf((float)cntg[gid], 1.0f);
    float v = pooled[(size_t)gid * 64 + lane] / c * fc_w[lane];
#pragma unroll
    for (int off = 32; off > 0; off >>= 1) v += __shfl_down(v, off);
    if (lane == 0) out[gid] = v + fc_b[0];
}

// ---------------------------------------------------------------- launch
extern "C" void kernel_launch(void* const* d_in, const int* in_sizes, int n_in,
                              void* d_out, int out_size, void* d_ws, size_t ws_size,
                              hipStream_t stream) {
    const float* x    = (const float*)d_in[0];
    const int*   eidx = (const int*)d_in[1];     // [2, E] flat: src row then dst row
    const int*   batch= (const int*)d_in[2];
    const float* W1   = (const float*)d_in[4];
    const float* b1   = (const float*)d_in[5];
    const float* W2   = (const float*)d_in[6];
    const float* b2   = (const float*)d_in[7];
    const float* fc_w = (const float*)d_in[8];
    const float* fc_b = (const float*)d_in[9];
    float* out = (float*)d_out;

    const int N = in_sizes[0] / IN_FEAT;
    const int E = in_sizes[1] / 2;
    const int G = N_GRAPHS;
    const int* src = eidx;
    const int* dst = eidx + E;

    // workspace carve
    char* w = (char*)d_ws;
    float* g1   = (float*)w; w += (size_t)N * 64 * 4;   // dinv * (x @ W1)
    float* h1r  = (float*)w; w += (size_t)N * 64 * 4;   // relu(conv1)
    float* g2   = (float*)w; w += (size_t)N * 64 * 4;   // dinv * (h1r @ W2)
    int*   degi = (int*)w;   w += (size_t)N * 4;
    float* dinv = (float*)w; w += (size_t)N * 4;
    int*   rowst= (int*)w;   w += (size_t)N * 4;
    int*   cur  = (int*)w;   w += (size_t)N * 4;
    int*   bsums= (int*)w;   w += 4096;
    int*   csrs = (int*)w;   w += (size_t)E * 4;
    float* pooled = (float*)w; w += (size_t)G * 64 * 4;
    int*   cntg = (int*)w;   w += (size_t)G * 4;

    const int nb_scan = (N + SCAN_CHUNK - 1) / SCAN_CHUNK;

    zero_u32<<<(G * 64 + 255) / 256, 256, 0, stream>>>((unsigned*)pooled, G * 64);
    zero_u32<<<(G + 255) / 256, 256, 0, stream>>>((unsigned*)cntg, G);
    init_deg<<<(N + 255) / 256, 256, 0, stream>>>(degi, N);
    count_graphs<<<(N + 255) / 256, 256, 0, stream>>>(batch, cntg, N);
    deg_count<<<(E / 4 + 255) / 256, 256, 0, stream>>>(dst, degi, E);
    compute_dinv<<<(N + 255) / 256, 256, 0, stream>>>(degi, dinv, N);
    scan_block_sums<<<nb_scan, 256, 0, stream>>>(degi, bsums, N);
    scan_bsums<<<1, 64, 0, stream>>>(bsums, nb_scan);
    scan_write<<<nb_scan, 256, 0, stream>>>(degi, bsums, rowst, cur, N);
    csr_fill<<<(E + 255) / 256, 256, 0, stream>>>(src, dst, cur, csrs, E);

    gemm_xw<IN_FEAT><<<(N + 127) / 128, 256, 0, stream>>>(x, W1, dinv, g1, N);
    gcn_gather<true, false><<<(N * 64 + 255) / 256, 256, 0, stream>>>(
        g1, dinv, rowst, degi, csrs, b1, h1r, nullptr, batch, N);
    gemm_xw<HIDDEN><<<(N + 127) / 128, 256, 0, stream>>>(h1r, W2, dinv, g2, N);
    gcn_gather<false, true><<<(N * 64 + 255) / 256, 256, 0, stream>>>(
        g2, dinv, rowst, degi, csrs, b2, nullptr, pooled, batch, N);
    final_fc<<<(G * 64 + 255) / 256, 256, 0, stream>>>(pooled, cntg, fc_w, fc_b, out, G);
}

// Round 3
// 1014.143 us; speedup vs baseline: 1.1777x; 1.1777x over previous
//
#include <hip/hip_runtime.h>
#include <hip/hip_bf16.h>

#define N_NODES  100000
#define N_EDGES  3200000
#define IN_FEAT  512
#define HIDDEN   64
#define N_GRAPHS 2048

// ---------------------------------------------------------------- utilities
__global__ __launch_bounds__(256) void zero_u32(unsigned* __restrict__ p, int n) {
    int i = blockIdx.x * 256 + threadIdx.x;
    if (i < n) p[i] = 0u;
}

__global__ __launch_bounds__(256) void init_deg(int* __restrict__ degi, int n) {
    int i = blockIdx.x * 256 + threadIdx.x;
    if (i < n) degi[i] = 1;              // self-loop contributes 1 to in-degree
}

// 4 edges per thread; capture atomic return as the edge's rank within its dst
__global__ __launch_bounds__(256) void deg_rank(const int* __restrict__ dst,
                                                int* __restrict__ degi,
                                                int* __restrict__ rank, int e) {
    int i = (blockIdx.x * 256 + threadIdx.x) * 4;
    if (i + 4 <= e) {
        int4 d = *(const int4*)(dst + i);
        int4 r;
        r.x = atomicAdd(&degi[d.x], 1);
        r.y = atomicAdd(&degi[d.y], 1);
        r.z = atomicAdd(&degi[d.z], 1);
        r.w = atomicAdd(&degi[d.w], 1);
        *(int4*)(rank + i) = r;
    } else {
        for (int j = i; j < e; j++) rank[j] = atomicAdd(&degi[dst[j]], 1);
    }
}

__global__ __launch_bounds__(256) void compute_dinv(const int* __restrict__ degi,
                                                    float* __restrict__ dinv, int n) {
    int i = blockIdx.x * 256 + threadIdx.x;
    if (i < n) dinv[i] = 1.0f / sqrtf((float)degi[i]);
}

__global__ __launch_bounds__(256) void count_graphs(const int* __restrict__ batch,
                                                    int* __restrict__ cntg, int n) {
    int i = blockIdx.x * 256 + threadIdx.x;
    if (i < n) atomicAdd(&cntg[batch[i]], 1);
}

// ---------------------------------------------------------------- scan (CSR offsets)
#define SCAN_CHUNK 2048

__global__ __launch_bounds__(256) void scan_block_sums(const int* __restrict__ degi,
                                                       int* __restrict__ bsums, int n) {
    __shared__ int sdata[256];
    int t = threadIdx.x;
    int base = blockIdx.x * SCAN_CHUNK;
    int s = 0;
    for (int i = 0; i < 8; i++) {
        int idx = base + t * 8 + i;
        if (idx < n) s += degi[idx] - 1;
    }
    sdata[t] = s;
    __syncthreads();
    for (int off = 128; off > 0; off >>= 1) {
        if (t < off) sdata[t] += sdata[t + off];
        __syncthreads();
    }
    if (t == 0) bsums[blockIdx.x] = sdata[0];
}

__global__ void scan_bsums(int* __restrict__ bsums, int nb) {
    if (blockIdx.x == 0 && threadIdx.x == 0) {
        int acc = 0;
        for (int i = 0; i < nb; i++) { int v = bsums[i]; bsums[i] = acc; acc += v; }
    }
}

__global__ __launch_bounds__(256) void scan_write(const int* __restrict__ degi,
                                                  const int* __restrict__ bsums,
                                                  int* __restrict__ row_start, int n) {
    __shared__ int sthread[256];
    int t = threadIdx.x;
    int base = blockIdx.x * SCAN_CHUNK;
    int local[8];
    int s = 0;
    for (int i = 0; i < 8; i++) {
        int idx = base + t * 8 + i;
        int c = (idx < n) ? (degi[idx] - 1) : 0;
        local[i] = s;
        s += c;
    }
    sthread[t] = s;
    __syncthreads();
    for (int off = 1; off < 256; off <<= 1) {
        int v = (t >= off) ? sthread[t - off] : 0;
        __syncthreads();
        sthread[t] += v;
        __syncthreads();
    }
    int off0 = bsums[blockIdx.x] + sthread[t] - s;   // exclusive prefix for this thread
    for (int i = 0; i < 8; i++) {
        int idx = base + t * 8 + i;
        if (idx < n) row_start[idx] = off0 + local[i];
    }
}

// atomic-free CSR fill: slot = row_start[d] + rank - 1 (rank starts at 1)
__global__ __launch_bounds__(256) void csr_scatter(const int* __restrict__ src,
                                                   const int* __restrict__ dst,
                                                   const int* __restrict__ rank,
                                                   const int* __restrict__ rowst,
                                                   int* __restrict__ csr_src, int e) {
    int i = (blockIdx.x * 256 + threadIdx.x) * 4;
    if (i + 4 <= e) {
        int4 d = *(const int4*)(dst + i);
        int4 s = *(const int4*)(src + i);
        int4 r = *(const int4*)(rank + i);
        csr_src[rowst[d.x] + r.x - 1] = s.x;
        csr_src[rowst[d.y] + r.y - 1] = s.y;
        csr_src[rowst[d.z] + r.z - 1] = s.z;
        csr_src[rowst[d.w] + r.w - 1] = s.w;
    } else {
        for (int j = i; j < e; j++)
            csr_src[rowst[dst[j]] + rank[j] - 1] = src[j];
    }
}

// ---------------------------------------------------------------- fp32 GEMM: Y[n,64] = dinv[n] * (X[n,K] @ W[K,64])
template <int K>
__global__ __launch_bounds__(256) void gemm_xw(const float* __restrict__ X,
                                               const float* __restrict__ W,
                                               const float* __restrict__ dinv,
                                               float* __restrict__ Y, int nrows) {
    constexpr int BM = 128;
    __shared__ float xs[BM][68];   // [row][k] pad 64 -> 68
    __shared__ float ws[64][64];   // [k][col]
    const int t = threadIdx.x;
    const int row0 = blockIdx.x * BM;
    const int ct = t & 15;         // cols ct*4 .. ct*4+3
    const int rt = t >> 4;         // rows rt + 16*j, j = 0..7
    float acc[8][4] = {};

#pragma unroll 1
    for (int k0 = 0; k0 < K; k0 += 64) {
#pragma unroll
        for (int p = 0; p < 4; p++) {
            int f = t + p * 256;
            int kk = f >> 4, cq = f & 15;
            *(float4*)&ws[kk][cq * 4] =
                *(const float4*)(W + (size_t)(k0 + kk) * 64 + cq * 4);
        }
#pragma unroll
        for (int p = 0; p < 8; p++) {
            int f = t + p * 256;
            int r = f >> 4, kq = f & 15;
            int gr = row0 + r;
            float4 v = make_float4(0.f, 0.f, 0.f, 0.f);
            if (gr < nrows) v = *(const float4*)(X + (size_t)gr * K + k0 + kq * 4);
            *(float4*)&xs[r][kq * 4] = v;
        }
        __syncthreads();

#pragma unroll
        for (int kq = 0; kq < 16; kq++) {
            float4 wv0 = *(float4*)&ws[kq * 4 + 0][ct * 4];
            float4 wv1 = *(float4*)&ws[kq * 4 + 1][ct * 4];
            float4 wv2 = *(float4*)&ws[kq * 4 + 2][ct * 4];
            float4 wv3 = *(float4*)&ws[kq * 4 + 3][ct * 4];
#pragma unroll
            for (int j = 0; j < 8; j++) {
                float4 xv = *(float4*)&xs[rt + 16 * j][kq * 4];
                acc[j][0] = fmaf(xv.x, wv0.x, acc[j][0]);
                acc[j][1] = fmaf(xv.x, wv0.y, acc[j][1]);
                acc[j][2] = fmaf(xv.x, wv0.z, acc[j][2]);
                acc[j][3] = fmaf(xv.x, wv0.w, acc[j][3]);
                acc[j][0] = fmaf(xv.y, wv1.x, acc[j][0]);
                acc[j][1] = fmaf(xv.y, wv1.y, acc[j][1]);
                acc[j][2] = fmaf(xv.y, wv1.z, acc[j][2]);
                acc[j][3] = fmaf(xv.y, wv1.w, acc[j][3]);
                acc[j][0] = fmaf(xv.z, wv2.x, acc[j][0]);
                acc[j][1] = fmaf(xv.z, wv2.y, acc[j][1]);
                acc[j][2] = fmaf(xv.z, wv2.z, acc[j][2]);
                acc[j][3] = fmaf(xv.z, wv2.w, acc[j][3]);
                acc[j][0] = fmaf(xv.w, wv3.x, acc[j][0]);
                acc[j][1] = fmaf(xv.w, wv3.y, acc[j][1]);
                acc[j][2] = fmaf(xv.w, wv3.z, acc[j][2]);
                acc[j][3] = fmaf(xv.w, wv3.w, acc[j][3]);
            }
        }
        __syncthreads();
    }

#pragma unroll
    for (int j = 0; j < 8; j++) {
        int gr = row0 + rt + 16 * j;
        if (gr < nrows) {
            float dv = dinv[gr];
            *(float4*)(Y + (size_t)gr * 64 + ct * 4) =
                make_float4(acc[j][0] * dv, acc[j][1] * dv, acc[j][2] * dv, acc[j][3] * dv);
        }
    }
}

// ---------------------------------------------------------------- GCN gather, wave per node, float4 lanes
// lane = fg (0..15, feature group of 4) + 16*es (0..3, edge slot)
// out[n,f] = dinv[n]*(g[n,f] + sum_src g[src,f]) + bias[f]
template <bool RELU, bool POOL>
__global__ __launch_bounds__(256) void gcn_gather(const float* __restrict__ g,
                                                  const float* __restrict__ dinv,
                                                  const int* __restrict__ row_start,
                                                  const int* __restrict__ degi,
                                                  const int* __restrict__ csr_src,
                                                  const float* __restrict__ bias,
                                                  float* __restrict__ out,
                                                  float* __restrict__ pooled,
                                                  const int* __restrict__ batch, int n) {
    int node = (blockIdx.x * 256 + threadIdx.x) >> 6;
    int lane = threadIdx.x & 63;
    int es = lane >> 4;
    int fg = lane & 15;
    if (node >= n) return;

    int start = row_start[node];
    int de = degi[node] - 1;
    float dn = dinv[node];

    float4 a0 = make_float4(0.f, 0.f, 0.f, 0.f);
    float4 a1 = a0, a2 = a0, a3 = a0;
    if (es == 0) a0 = *(const float4*)(g + (size_t)node * 64 + fg * 4);  // self-loop

    for (int c = 0; c < de; c += 64) {
        int m = min(64, de - c);
        int sv = (lane < m) ? csr_src[start + c + lane] : -1;
        int t = 0;
        for (; t + 16 <= m; t += 16) {
            int s0 = __shfl(sv, t + es);
            int s1 = __shfl(sv, t + 4 + es);
            int s2 = __shfl(sv, t + 8 + es);
            int s3 = __shfl(sv, t + 12 + es);
            float4 v0 = *(const float4*)(g + (size_t)s0 * 64 + fg * 4);
            float4 v1 = *(const float4*)(g + (size_t)s1 * 64 + fg * 4);
            float4 v2 = *(const float4*)(g + (size_t)s2 * 64 + fg * 4);
            float4 v3 = *(const float4*)(g + (size_t)s3 * 64 + fg * 4);
            a0.x += v0.x; a0.y += v0.y; a0.z += v0.z; a0.w += v0.w;
            a1.x += v1.x; a1.y += v1.y; a1.z += v1.z; a1.w += v1.w;
            a2.x += v2.x; a2.y += v2.y; a2.z += v2.z; a2.w += v2.w;
            a3.x += v3.x; a3.y += v3.y; a3.z += v3.w == v3.w ? v3.z : v3.z; a3.w += v3.w; // (no-op guard removed below)
        }
        for (; t < m; t += 4) {
            int e = t + es;                 // <= 63 always
            int s = __shfl(sv, e);
            if (e < m) {
                float4 v = *(const float4*)(g + (size_t)s * 64 + fg * 4);
                a0.x += v.x; a0.y += v.y; a0.z += v.z; a0.w += v.w;
            }
        }
    }
    float4 a;
    a.x = (a0.x + a1.x) + (a2.x + a3.x);
    a.y = (a0.y + a1.y) + (a2.y + a3.y);
    a.z = (a0.z + a1.z) + (a2.z + a3.z);
    a.w = (a0.w + a1.w) + (a2.w + a3.w);
    // reduce across the 4 edge-slot groups (lane ^ 16, lane ^ 32)
    a.x += __shfl_xor(a.x, 16); a.y += __shfl_xor(a.y, 16);
    a.z += __shfl_xor(a.z, 16); a.w += __shfl_xor(a.w, 16);
    a.x += __shfl_xor(a.x, 32); a.y += __shfl_xor(a.y, 32);
    a.z += __shfl_xor(a.z, 32); a.w += __shfl_xor(a.w, 32);

    if (es == 0) {
        float4 bv = *(const float4*)(bias + fg * 4);
        float4 o;
        o.x = fmaf(dn, a.x, bv.x);
        o.y = fmaf(dn, a.y, bv.y);
        o.z = fmaf(dn, a.z, bv.z);
        o.w = fmaf(dn, a.w, bv.w);
        if (RELU) {
            o.x = fmaxf(o.x, 0.f); o.y = fmaxf(o.y, 0.f);
            o.z = fmaxf(o.z, 0.f); o.w = fmaxf(o.w, 0.f);
        }
        if (POOL) {
            float* pp = pooled + (size_t)batch[node] * 64 + fg * 4;
            atomicAdd(pp + 0, o.x);
            atomicAdd(pp + 1, o.y);
            atomicAdd(pp + 2, o.z);
            atomicAdd(pp + 3, o.w);
        } else {
            *(float4*)(out + (size_t)node * 64 + fg * 4) = o;
        }
    }
}

// ---------------------------------------------------------------- final FC, wave per graph
__global__ __launch_bounds__(256) void final_fc(const float* __restrict__ pooled,
                                                const int* __restrict__ cntg,
                                                const float* __restrict__ fc_w,
                                                const float* __restrict__ fc_b,
                                                float* __restrict__ out, int g) {
    int gid = (blockIdx.x * 256 + threadIdx.x) >> 6;
    int lane = threadIdx.x & 63;
    if (gid >= g) return;
    float c = fmaxf((float)cntg[gid], 1.0f);
    float v = pooled[(size_t)gid * 64 + lane] / c * fc_w[lane];
#pragma unroll
    for (int off = 32; off > 0; off >>= 1) v += __shfl_down(v, off);
    if (lane == 0) out[gid] = v + fc_b[0];
}

// ---------------------------------------------------------------- launch
extern "C" void kernel_launch(void* const* d_in, const int* in_sizes, int n_in,
                              void* d_out, int out_size, void* d_ws, size_t ws_size,
                              hipStream_t stream) {
    const float* x    = (const float*)d_in[0];
    const int*   eidx = (const int*)d_in[1];     // [2, E] flat: src row then dst row
    const int*   batch= (const int*)d_in[2];
    const float* W1   = (const float*)d_in[4];
    const float* b1   = (const float*)d_in[5];
    const float* W2   = (const float*)d_in[6];
    const float* b2   = (const float*)d_in[7];
    const float* fc_w = (const float*)d_in[8];
    const float* fc_b = (const float*)d_in[9];
    float* out = (float*)d_out;

    const int N = in_sizes[0] / IN_FEAT;
    const int E = in_sizes[1] / 2;
    const int G = N_GRAPHS;
    const int* src = eidx;
    const int* dst = eidx + E;

    // workspace carve
    char* w = (char*)d_ws;
    float* g1   = (float*)w; w += (size_t)N * 64 * 4;   // dinv * (x @ W1)
    float* h1r  = (float*)w; w += (size_t)N * 64 * 4;   // relu(conv1)
    float* g2   = (float*)w; w += (size_t)N * 64 * 4;   // dinv * (h1r @ W2)
    int*   degi = (int*)w;   w += (size_t)N * 4;
    float* dinv = (float*)w; w += (size_t)N * 4;
    int*   rowst= (int*)w;   w += (size_t)N * 4;
    int*   bsums= (int*)w;   w += 4096;
    int*   csrs = (int*)w;   w += (size_t)E * 4;
    int*   rank = (int*)w;   w += (size_t)E * 4;
    float* pooled = (float*)w; w += (size_t)G * 64 * 4;
    int*   cntg = (int*)w;   w += (size_t)G * 4;

    const int nb_scan = (N + SCAN_CHUNK - 1) / SCAN_CHUNK;

    zero_u32<<<(G * 64 + 255) / 256, 256, 0, stream>>>((unsigned*)pooled, G * 64);
    zero_u32<<<(G + 255) / 256, 256, 0, stream>>>((unsigned*)cntg, G);
    init_deg<<<(N + 255) / 256, 256, 0, stream>>>(degi, N);
    count_graphs<<<(N + 255) / 256, 256, 0, stream>>>(batch, cntg, N);
    deg_rank<<<(E / 4 + 255) / 256, 256, 0, stream>>>(dst, degi, rank, E);
    compute_dinv<<<(N + 255) / 256, 256, 0, stream>>>(degi, dinv, N);
    scan_block_sums<<<nb_scan, 256, 0, stream>>>(degi, bsums, N);
    scan_bsums<<<1, 64, 0, stream>>>(bsums, nb_scan);
    scan_write<<<nb_scan, 256, 0, stream>>>(degi, bsums, rowst, N);
    csr_scatter<<<(E / 4 + 255) / 256, 256, 0, stream>>>(src, dst, rank, rowst, csrs, E);

    gemm_xw<IN_FEAT><<<(N + 127) / 128, 256, 0, stream>>>(x, W1, dinv, g1, N);
    gcn_gather<true, false><<<(N * 64 + 255) / 256, 256, 0, stream>>>(
        g1, dinv, rowst, degi, csrs, b1, h1r, nullptr, batch, N);
    gemm_xw<HIDDEN><<<(N + 127) / 128, 256, 0, stream>>>(h1r, W2, dinv, g2, N);
    gcn_gather<false, true><<<(N * 64 + 255) / 256, 256, 0, stream>>>(
        g2, dinv, rowst, degi, csrs, b2, nullptr, pooled, batch, N);
    final_fc<<<(G * 64 + 255) / 256, 256, 0, stream>>>(pooled, cntg, fc_w, fc_b, out, G);
}

// Round 4
// 811.417 us; speedup vs baseline: 1.4719x; 1.2498x over previous
//
#include <hip/hip_runtime.h>
#include <hip/hip_bf16.h>

#define N_NODES  100000
#define N_EDGES  3200000
#define IN_FEAT  512
#define HIDDEN   64
#define N_GRAPHS 2048

typedef __attribute__((ext_vector_type(8))) short short8;
typedef __attribute__((ext_vector_type(4))) float floatx4;

// ---------------------------------------------------------------- utilities
__global__ __launch_bounds__(256) void zero_u32(unsigned* __restrict__ p, int n) {
    int i = blockIdx.x * 256 + threadIdx.x;
    if (i < n) p[i] = 0u;
}

__global__ __launch_bounds__(256) void init_deg(int* __restrict__ degi, int n) {
    int i = blockIdx.x * 256 + threadIdx.x;
    if (i < n) degi[i] = 1;              // self-loop contributes 1 to in-degree
}

// 4 edges per thread; capture atomic return as the edge's rank within its dst
__global__ __launch_bounds__(256) void deg_rank(const int* __restrict__ dst,
                                                int* __restrict__ degi,
                                                int* __restrict__ rank, int e) {
    int i = (blockIdx.x * 256 + threadIdx.x) * 4;
    if (i + 4 <= e) {
        int4 d = *(const int4*)(dst + i);
        int4 r;
        r.x = atomicAdd(&degi[d.x], 1);
        r.y = atomicAdd(&degi[d.y], 1);
        r.z = atomicAdd(&degi[d.z], 1);
        r.w = atomicAdd(&degi[d.w], 1);
        *(int4*)(rank + i) = r;
    } else {
        for (int j = i; j < e; j++) rank[j] = atomicAdd(&degi[dst[j]], 1);
    }
}

__global__ __launch_bounds__(256) void compute_dinv(const int* __restrict__ degi,
                                                    float* __restrict__ dinv, int n) {
    int i = blockIdx.x * 256 + threadIdx.x;
    if (i < n) dinv[i] = 1.0f / sqrtf((float)degi[i]);
}

__global__ __launch_bounds__(256) void count_graphs(const int* __restrict__ batch,
                                                    int* __restrict__ cntg, int n) {
    int i = blockIdx.x * 256 + threadIdx.x;
    if (i < n) atomicAdd(&cntg[batch[i]], 1);
}

// ---------------------------------------------------------------- scan (CSR offsets)
#define SCAN_CHUNK 2048

__global__ __launch_bounds__(256) void scan_block_sums(const int* __restrict__ degi,
                                                       int* __restrict__ bsums, int n) {
    __shared__ int sdata[256];
    int t = threadIdx.x;
    int base = blockIdx.x * SCAN_CHUNK;
    int s = 0;
    for (int i = 0; i < 8; i++) {
        int idx = base + t * 8 + i;
        if (idx < n) s += degi[idx] - 1;
    }
    sdata[t] = s;
    __syncthreads();
    for (int off = 128; off > 0; off >>= 1) {
        if (t < off) sdata[t] += sdata[t + off];
        __syncthreads();
    }
    if (t == 0) bsums[blockIdx.x] = sdata[0];
}

__global__ void scan_bsums(int* __restrict__ bsums, int nb) {
    if (blockIdx.x == 0 && threadIdx.x == 0) {
        int acc = 0;
        for (int i = 0; i < nb; i++) { int v = bsums[i]; bsums[i] = acc; acc += v; }
    }
}

__global__ __launch_bounds__(256) void scan_write(const int* __restrict__ degi,
                                                  const int* __restrict__ bsums,
                                                  int* __restrict__ row_start, int n) {
    __shared__ int sthread[256];
    int t = threadIdx.x;
    int base = blockIdx.x * SCAN_CHUNK;
    int local[8];
    int s = 0;
    for (int i = 0; i < 8; i++) {
        int idx = base + t * 8 + i;
        int c = (idx < n) ? (degi[idx] - 1) : 0;
        local[i] = s;
        s += c;
    }
    sthread[t] = s;
    __syncthreads();
    for (int off = 1; off < 256; off <<= 1) {
        int v = (t >= off) ? sthread[t - off] : 0;
        __syncthreads();
        sthread[t] += v;
        __syncthreads();
    }
    int off0 = bsums[blockIdx.x] + sthread[t] - s;   // exclusive prefix for this thread
    for (int i = 0; i < 8; i++) {
        int idx = base + t * 8 + i;
        if (idx < n) row_start[idx] = off0 + local[i];
    }
}

// atomic-free CSR fill: slot = row_start[d] + rank - 1 (rank starts at 1)
__global__ __launch_bounds__(256) void csr_scatter(const int* __restrict__ src,
                                                   const int* __restrict__ dst,
                                                   const int* __restrict__ rank,
                                                   const int* __restrict__ rowst,
                                                   int* __restrict__ csr_src, int e) {
    int i = (blockIdx.x * 256 + threadIdx.x) * 4;
    if (i + 4 <= e) {
        int4 d = *(const int4*)(dst + i);
        int4 s = *(const int4*)(src + i);
        int4 r = *(const int4*)(rank + i);
        csr_src[rowst[d.x] + r.x - 1] = s.x;
        csr_src[rowst[d.y] + r.y - 1] = s.y;
        csr_src[rowst[d.z] + r.z - 1] = s.z;
        csr_src[rowst[d.w] + r.w - 1] = s.w;
    } else {
        for (int j = i; j < e; j++)
            csr_src[rowst[dst[j]] + rank[j] - 1] = src[j];
    }
}

// ---------------------------------------------------------------- split-bf16 MFMA GEMM
// Y[n,64] = dinv[n] * (X[n,K] @ W[K,64]); X,W fp32 decomposed as hi+lo bf16;
// acc = Xhi*Whi + Xhi*Wlo + Xlo*Whi (fp32 MFMA accumulate).
// block = 256 thr = 4 waves; wave w owns rows [blk*64 + 16w, +16); K-chunk = 32.
__device__ inline void bf16_split(float f, short& hi, short& lo) {
    unsigned u = __float_as_uint(f);
    unsigned r = (u + 0x7fffu + ((u >> 16) & 1u)) >> 16;     // RNE to bf16
    float fh = __uint_as_float(r << 16);
    float fl = f - fh;                                        // exact
    unsigned v = __float_as_uint(fl);
    unsigned s = (v + 0x7fffu + ((v >> 16) & 1u)) >> 16;
    hi = (short)r;
    lo = (short)s;
}

template <int K>
__global__ __launch_bounds__(256) void gemm_mfma(const float* __restrict__ X,
                                                 const float* __restrict__ W,
                                                 const float* __restrict__ dinv,
                                                 float* __restrict__ Y, int nrows) {
    constexpr int BSTR = 40;                   // bf16 elems per col (32 + 8 pad), 80 B
    __shared__ short bhi[64 * BSTR];
    __shared__ short blo[64 * BSTR];

    const int t    = threadIdx.x;
    const int wave = t >> 6;
    const int lane = t & 63;
    const int quad = lane >> 4;
    const int l16  = lane & 15;

    const int arow   = blockIdx.x * 64 + wave * 16 + l16;  // A-fragment row
    const bool rvalid = arow < nrows;
    const float* xrow = X + (size_t)arow * K;

    // staging role: col = t&63, k-group = t>>6
    const int scol = t & 63;
    const int skg  = t >> 6;

    floatx4 acc[4] = {};

#pragma unroll 1
    for (int k0 = 0; k0 < K; k0 += 32) {
        // -- load W[k0+skg*8+j][scol], coalesced 256B rows
        float wv[8];
#pragma unroll
        for (int j = 0; j < 8; j++)
            wv[j] = W[(size_t)(k0 + skg * 8 + j) * 64 + scol];
        short8 whi, wlo;
#pragma unroll
        for (int j = 0; j < 8; j++) { short h, l; bf16_split(wv[j], h, l); whi[j] = h; wlo[j] = l; }

        __syncthreads();   // prior chunk's B reads complete before overwrite
        *(short8*)&bhi[scol * BSTR + skg * 8] = whi;
        *(short8*)&blo[scol * BSTR + skg * 8] = wlo;

        // -- A fragment: X[arow][k0 + quad*8 .. +7] direct from global
        float av[8] = {0.f, 0.f, 0.f, 0.f, 0.f, 0.f, 0.f, 0.f};
        if (rvalid) {
            float4 p0 = *(const float4*)(xrow + k0 + quad * 8);
            float4 p1 = *(const float4*)(xrow + k0 + quad * 8 + 4);
            av[0] = p0.x; av[1] = p0.y; av[2] = p0.z; av[3] = p0.w;
            av[4] = p1.x; av[5] = p1.y; av[6] = p1.z; av[7] = p1.w;
        }
        short8 ahi, alo;
#pragma unroll
        for (int j = 0; j < 8; j++) { short h, l; bf16_split(av[j], h, l); ahi[j] = h; alo[j] = l; }

        __syncthreads();   // B staged

#pragma unroll
        for (int ct = 0; ct < 4; ct++) {
            int col = ct * 16 + l16;
            short8 bh = *(short8*)&bhi[col * BSTR + quad * 8];
            short8 bl = *(short8*)&blo[col * BSTR + quad * 8];
            acc[ct] = __builtin_amdgcn_mfma_f32_16x16x32_bf16(ahi, bh, acc[ct], 0, 0, 0);
            acc[ct] = __builtin_amdgcn_mfma_f32_16x16x32_bf16(ahi, bl, acc[ct], 0, 0, 0);
            acc[ct] = __builtin_amdgcn_mfma_f32_16x16x32_bf16(alo, bh, acc[ct], 0, 0, 0);
        }
    }

    // C/D layout: col = ct*16 + l16, row = wave*16 + quad*4 + r
#pragma unroll
    for (int r = 0; r < 4; r++) {
        int orow = blockIdx.x * 64 + wave * 16 + quad * 4 + r;
        if (orow < nrows) {
            float dv = dinv[orow];
#pragma unroll
            for (int ct = 0; ct < 4; ct++)
                Y[(size_t)orow * 64 + ct * 16 + l16] = acc[ct][r] * dv;
        }
    }
}

// ---------------------------------------------------------------- GCN gather, wave per node, float4 lanes
// lane = fg (0..15, feature group of 4) + 16*es (0..3, edge slot)
// out[n,f] = dinv[n]*(g[n,f] + sum_src g[src,f]) + bias[f]
template <bool RELU, bool POOL>
__global__ __launch_bounds__(256) void gcn_gather(const float* __restrict__ g,
                                                  const float* __restrict__ dinv,
                                                  const int* __restrict__ row_start,
                                                  const int* __restrict__ degi,
                                                  const int* __restrict__ csr_src,
                                                  const float* __restrict__ bias,
                                                  float* __restrict__ out,
                                                  float* __restrict__ pooled,
                                                  const int* __restrict__ batch, int n) {
    int node = (blockIdx.x * 256 + threadIdx.x) >> 6;
    int lane = threadIdx.x & 63;
    int es = lane >> 4;
    int fg = lane & 15;
    if (node >= n) return;

    int start = row_start[node];
    int de = degi[node] - 1;
    float dn = dinv[node];

    float4 a0 = make_float4(0.f, 0.f, 0.f, 0.f);
    float4 a1 = a0, a2 = a0, a3 = a0;
    if (es == 0) a0 = *(const float4*)(g + (size_t)node * 64 + fg * 4);  // self-loop

    for (int c = 0; c < de; c += 64) {
        int m = min(64, de - c);
        int sv = (lane < m) ? csr_src[start + c + lane] : -1;
        int t = 0;
        for (; t + 16 <= m; t += 16) {
            int s0 = __shfl(sv, t + es);
            int s1 = __shfl(sv, t + 4 + es);
            int s2 = __shfl(sv, t + 8 + es);
            int s3 = __shfl(sv, t + 12 + es);
            float4 v0 = *(const float4*)(g + (size_t)s0 * 64 + fg * 4);
            float4 v1 = *(const float4*)(g + (size_t)s1 * 64 + fg * 4);
            float4 v2 = *(const float4*)(g + (size_t)s2 * 64 + fg * 4);
            float4 v3 = *(const float4*)(g + (size_t)s3 * 64 + fg * 4);
            a0.x += v0.x; a0.y += v0.y; a0.z += v0.z; a0.w += v0.w;
            a1.x += v1.x; a1.y += v1.y; a1.z += v1.z; a1.w += v1.w;
            a2.x += v2.x; a2.y += v2.y; a2.z += v2.z; a2.w += v2.w;
            a3.x += v3.x; a3.y += v3.y; a3.z += v3.z; a3.w += v3.w;
        }
        for (; t < m; t += 4) {
            int e = t + es;                 // <= 63 always
            int s = __shfl(sv, e);
            if (e < m) {
                float4 v = *(const float4*)(g + (size_t)s * 64 + fg * 4);
                a0.x += v.x; a0.y += v.y; a0.z += v.z; a0.w += v.w;
            }
        }
    }
    float4 a;
    a.x = (a0.x + a1.x) + (a2.x + a3.x);
    a.y = (a0.y + a1.y) + (a2.y + a3.y);
    a.z = (a0.z + a1.z) + (a2.z + a3.z);
    a.w = (a0.w + a1.w) + (a2.w + a3.w);
    // reduce across the 4 edge-slot groups (lane ^ 16, lane ^ 32)
    a.x += __shfl_xor(a.x, 16); a.y += __shfl_xor(a.y, 16);
    a.z += __shfl_xor(a.z, 16); a.w += __shfl_xor(a.w, 16);
    a.x += __shfl_xor(a.x, 32); a.y += __shfl_xor(a.y, 32);
    a.z += __shfl_xor(a.z, 32); a.w += __shfl_xor(a.w, 32);

    if (es == 0) {
        float4 bv = *(const float4*)(bias + fg * 4);
        float4 o;
        o.x = fmaf(dn, a.x, bv.x);
        o.y = fmaf(dn, a.y, bv.y);
        o.z = fmaf(dn, a.z, bv.z);
        o.w = fmaf(dn, a.w, bv.w);
        if (RELU) {
            o.x = fmaxf(o.x, 0.f); o.y = fmaxf(o.y, 0.f);
            o.z = fmaxf(o.z, 0.f); o.w = fmaxf(o.w, 0.f);
        }
        if (POOL) {
            float* pp = pooled + (size_t)batch[node] * 64 + fg * 4;
            atomicAdd(pp + 0, o.x);
            atomicAdd(pp + 1, o.y);
            atomicAdd(pp + 2, o.z);
            atomicAdd(pp + 3, o.w);
        } else {
            *(float4*)(out + (size_t)node * 64 + fg * 4) = o;
        }
    }
}

// ---------------------------------------------------------------- final FC, wave per graph
__global__ __launch_bounds__(256) void final_fc(const float* __restrict__ pooled,
                                                const int* __restrict__ cntg,
                                                const float* __restrict__ fc_w,
                                                const float* __restrict__ fc_b,
                                                float* __restrict__ out, int g) {
    int gid = (blockIdx.x * 256 + threadIdx.x) >> 6;
    int lane = threadIdx.x & 63;
    if (gid >= g) return;
    float c = fmaxf((float)cntg[gid], 1.0f);
    float v = pooled[(size_t)gid * 64 + lane] / c * fc_w[lane];
#pragma unroll
    for (int off = 32; off > 0; off >>= 1) v += __shfl_down(v, off);
    if (lane == 0) out[gid] = v + fc_b[0];
}

// ---------------------------------------------------------------- launch
extern "C" void kernel_launch(void* const* d_in, const int* in_sizes, int n_in,
                              void* d_out, int out_size, void* d_ws, size_t ws_size,
                              hipStream_t stream) {
    const float* x    = (const float*)d_in[0];
    const int*   eidx = (const int*)d_in[1];     // [2, E] flat: src row then dst row
    const int*   batch= (const int*)d_in[2];
    const float* W1   = (const float*)d_in[4];
    const float* b1   = (const float*)d_in[5];
    const float* W2   = (const float*)d_in[6];
    const float* b2   = (const float*)d_in[7];
    const float* fc_w = (const float*)d_in[8];
    const float* fc_b = (const float*)d_in[9];
    float* out = (float*)d_out;

    const int N = in_sizes[0] / IN_FEAT;
    const int E = in_sizes[1] / 2;
    const int G = N_GRAPHS;
    const int* src = eidx;
    const int* dst = eidx + E;

    // workspace carve
    char* w = (char*)d_ws;
    float* g1   = (float*)w; w += (size_t)N * 64 * 4;   // dinv * (x @ W1)
    float* h1r  = (float*)w; w += (size_t)N * 64 * 4;   // relu(conv1)
    float* g2   = (float*)w; w += (size_t)N * 64 * 4;   // dinv * (h1r @ W2)
    int*   degi = (int*)w;   w += (size_t)N * 4;
    float* dinv = (float*)w; w += (size_t)N * 4;
    int*   rowst= (int*)w;   w += (size_t)N * 4;
    int*   bsums= (int*)w;   w += 4096;
    int*   csrs = (int*)w;   w += (size_t)E * 4;
    int*   rank = (int*)w;   w += (size_t)E * 4;
    float* pooled = (float*)w; w += (size_t)G * 64 * 4;
    int*   cntg = (int*)w;   w += (size_t)G * 4;

    const int nb_scan = (N + SCAN_CHUNK - 1) / SCAN_CHUNK;

    zero_u32<<<(G * 64 + 255) / 256, 256, 0, stream>>>((unsigned*)pooled, G * 64);
    zero_u32<<<(G + 255) / 256, 256, 0, stream>>>((unsigned*)cntg, G);
    init_deg<<<(N + 255) / 256, 256, 0, stream>>>(degi, N);
    count_graphs<<<(N + 255) / 256, 256, 0, stream>>>(batch, cntg, N);
    deg_rank<<<(E / 4 + 255) / 256, 256, 0, stream>>>(dst, degi, rank, E);
    compute_dinv<<<(N + 255) / 256, 256, 0, stream>>>(degi, dinv, N);
    scan_block_sums<<<nb_scan, 256, 0, stream>>>(degi, bsums, N);
    scan_bsums<<<1, 64, 0, stream>>>(bsums, nb_scan);
    scan_write<<<nb_scan, 256, 0, stream>>>(degi, bsums, rowst, N);
    csr_scatter<<<(E / 4 + 255) / 256, 256, 0, stream>>>(src, dst, rank, rowst, csrs, E);

    gemm_mfma<IN_FEAT><<<(N + 63) / 64, 256, 0, stream>>>(x, W1, dinv, g1, N);
    gcn_gather<true, false><<<(N * 64 + 255) / 256, 256, 0, stream>>>(
        g1, dinv, rowst, degi, csrs, b1, h1r, nullptr, batch, N);
    gemm_mfma<HIDDEN><<<(N + 63) / 64, 256, 0, stream>>>(h1r, W2, dinv, g2, N);
    gcn_gather<false, true><<<(N * 64 + 255) / 256, 256, 0, stream>>>(
        g2, dinv, rowst, degi, csrs, b2, nullptr, pooled, batch, N);
    final_fc<<<(G * 64 + 255) / 256, 256, 0, stream>>>(pooled, cntg, fc_w, fc_b, out, G);
}